// Round 3
// baseline (5733.384 us; speedup 1.0000x reference)
//
#include <hip/hip_runtime.h>
#include <hip/hip_bf16.h>

// B=4, C=128, G=64, K=3, SC=512, H_hf=256, H_lf=128
#define BB 4
#define CCH 128
#define GRP 64
#define SCH 512
#define EPSV 1e-5f

typedef unsigned short u16;

__device__ __forceinline__ float b2f(u16 u) {
    return __uint_as_float(((unsigned int)u) << 16);
}
__device__ __forceinline__ u16 f2b(float f) {
    unsigned int u = __float_as_uint(f);
    return (u16)((u + 0x7fffu + ((u >> 16) & 1u)) >> 16);
}
__device__ __forceinline__ int refl(int i, int n) {
    if (i < 0) i = -i;
    if (i >= n) i = 2 * n - 2 - i;
    return i;
}
// dtype-flagged load/store: isbf=1 -> bf16 array, else f32 array
__device__ __forceinline__ float ldv(const void* p, long long i, int isbf) {
    return isbf ? b2f(((const u16*)p)[i]) : ((const float*)p)[i];
}
__device__ __forceinline__ void stv(void* p, long long i, int isbf, float v) {
    if (isbf) ((u16*)p)[i] = f2b(v);
    else ((float*)p)[i] = v;
}

// ---------------------------------------------------------------------------
// D0: dtype detector. Sample even u16 words of c_hf. If data is bf16, even
// words are bf16 values of N(0,1) samples (~99% of |v| in [0.004,8]). If f32,
// even words are low mantissa bits (uniform) -> ~5% in range.
__global__ __launch_bounds__(256) void detect_kernel(const void* x, int* flag) {
    const u16* p = (const u16*)x;
    int tid = threadIdx.x;
    int cnt = 0;
#pragma unroll
    for (int k = 0; k < 16; ++k) {
        float v = fabsf(b2f(p[2 * (tid * 16 + k)]));
        if (v > 0.004f && v < 8.0f) cnt++;
    }
    __shared__ int red[256];
    red[tid] = cnt;
    __syncthreads();
    for (int st = 128; st > 0; st >>= 1) {
        if (tid < st) red[tid] += red[tid + st];
        __syncthreads();
    }
    if (tid == 0) flag[0] = (red[0] >= 2048) ? 1 : 0;
}

// ---------------------------------------------------------------------------
// K0: per-(b,k) mean of 3x3 style map -> sm [B,512]
__global__ __launch_bounds__(256) void sm_kernel(const int* flag, const void* s, float* sm) {
    int idx = blockIdx.x * 256 + threadIdx.x;
    if (idx >= BB * SCH) return;
    int isbf = flag[0];
    float t = 0.f;
#pragma unroll
    for (int j = 0; j < 9; ++j) t += ldv(s, (long long)idx * 9 + j, isbf);
    sm[idx] = t * (1.0f / 9.0f);
}

// ---------------------------------------------------------------------------
// K1: spatial predictor: reflect-pad 3x3 -> 5x5, conv [256,512,3,3] -> wsp [B,256,9]
__global__ __launch_bounds__(256) void spconv_kernel(const int* flag, const void* s,
                                                     const void* sp_w, const void* sp_b,
                                                     float* wsp_out) {
    int isbf = flag[0];
    int b = blockIdx.x >> 8;
    int oc = blockIdx.x & 255;
    int tid = threadIdx.x;
    float acc[9];
#pragma unroll
    for (int o = 0; o < 9; ++o) acc[o] = 0.f;
    for (int ic = tid; ic < SCH; ic += 256) {
        float sv[9], wv[9];
#pragma unroll
        for (int j = 0; j < 9; ++j) sv[j] = ldv(s, (long long)(b * SCH + ic) * 9 + j, isbf);
#pragma unroll
        for (int j = 0; j < 9; ++j) wv[j] = ldv(sp_w, (long long)(oc * SCH + ic) * 9 + j, isbf);
        const int m[5] = {1, 0, 1, 2, 1};
#pragma unroll
        for (int oy = 0; oy < 3; ++oy) {
#pragma unroll
            for (int ox = 0; ox < 3; ++ox) {
                float t = 0.f;
#pragma unroll
                for (int kr = 0; kr < 3; ++kr)
#pragma unroll
                    for (int kc = 0; kc < 3; ++kc)
                        t += sv[m[oy + kr] * 3 + m[ox + kc]] * wv[kr * 3 + kc];
                acc[oy * 3 + ox] += t;
            }
        }
    }
    __shared__ float red[256];
#pragma unroll 1
    for (int o = 0; o < 9; ++o) {
        red[tid] = acc[o];
        __syncthreads();
        for (int st = 128; st > 0; st >>= 1) {
            if (tid < st) red[tid] += red[tid + st];
            __syncthreads();
        }
        if (tid == 0) wsp_out[(b * 256 + oc) * 9 + o] = red[0] + ldv(sp_b, oc, isbf);
        __syncthreads();
    }
}

// ---------------------------------------------------------------------------
// K2: pointwise weights + bias predictor (GEMV over 512)
__global__ __launch_bounds__(256) void pwbias_kernel(const int* flag, const float* __restrict__ sm,
                                                     const void* pw_w, const void* pw_b,
                                                     const void* b_w, const void* b_b,
                                                     float* wpw, float* biasout) {
    int idx = blockIdx.x * 256 + threadIdx.x;
    if (idx >= BB * 384) return;
    int isbf = flag[0];
    int b = idx / 384;
    int j = idx % 384;
    const float* smb = sm + b * SCH;
    if (j < 256) {
        float a = 0.f;
        for (int k = 0; k < SCH; ++k) a += smb[k] * ldv(pw_w, (long long)j * SCH + k, isbf);
        wpw[b * 256 + j] = a + ldv(pw_b, j, isbf);
    } else {
        int j2 = j - 256;
        float a = 0.f;
        for (int k = 0; k < SCH; ++k) a += smb[k] * ldv(b_w, (long long)j2 * SCH + k, isbf);
        biasout[b * CCH + j2] = a + ldv(b_b, j2, isbf);
    }
}

// ---------------------------------------------------------------------------
// K3: per-(b,c) mean / rstd over HW. One block per (b,c).
__global__ __launch_bounds__(256) void stats_kernel(const int* flag, const void* x, long long off,
                                                    float* stat, int HW) {
    int isbf = flag[0];
    int bc = blockIdx.x;
    int tid = threadIdx.x;
    long long base = off + (long long)bc * HW;
    float s = 0.f, s2 = 0.f;
    for (int i = tid; i < HW; i += 256) {
        float v = ldv(x, base + i, isbf);
        s += v;
        s2 += v * v;
    }
    __shared__ float rs[256];
    __shared__ float rq[256];
    rs[tid] = s;
    rq[tid] = s2;
    __syncthreads();
    for (int st = 128; st > 0; st >>= 1) {
        if (tid < st) { rs[tid] += rs[tid + st]; rq[tid] += rq[tid + st]; }
        __syncthreads();
    }
    if (tid == 0) {
        float inv = 1.0f / (float)HW;
        float mean = rs[0] * inv;
        float var = rq[0] * inv - mean * mean;
        stat[bc * 2] = mean;
        stat[bc * 2 + 1] = rsqrtf(var + EPSV);
    }
}

// ---------------------------------------------------------------------------
// K4: banded fused inorm + grouped spatial + grouped pointwise.
// Computes y2 (f32) for band rows r0-1 .. r0+32 (reflected), 34 rows, with the
// horizontal reflect-pad MATERIALIZED: padded col j (0..W+1) = y2 at true col
// refl(j-1, W). Row stride WS = W+8 keeps rows 16B-aligned for the consumer.
// band layout: [b*128+c][34][WS] f32
__global__ __launch_bounds__(256) void grouped_band_kernel(const int* flag, const void* x,
                                                           const float* __restrict__ xstat,
                                                           const float* __restrict__ wsp,
                                                           const float* __restrict__ wpw,
                                                           const float* __restrict__ bias,
                                                           float* __restrict__ band,
                                                           int H, int W, int WS, int r0) {
    int isbf = flag[0];
    int WP = W + 2;
    int ppb = (34 * WP + 255) >> 8;  // 256-thread blocks per (b,g)
    int t = blockIdx.x;
    int bg = t / ppb;
    int tile = t - bg * ppb;
    int b = bg >> 6;
    int g = bg & 63;
    int tid = threadIdx.x;

    __shared__ float sw[36], pw[4], bs[2], xm[2], xr[2];
    if (tid < 36) {
        int o = tid / 18, i = (tid % 18) / 9, k = tid % 9;
        sw[tid] = wsp[(b * 256 + (2 * g + o) * 2 + i) * 9 + k];
    }
    if (tid < 4) pw[tid] = wpw[b * 256 + (2 * g + (tid >> 1)) * 2 + (tid & 1)];
    if (tid < 2) {
        bs[tid] = bias[b * CCH + 2 * g + tid];
        xm[tid] = xstat[(b * CCH + 2 * g + tid) * 2];
        xr[tid] = xstat[(b * CCH + 2 * g + tid) * 2 + 1];
    }
    __syncthreads();

    int p = tile * 256 + tid;
    int j = p / WP;
    int colp = p - j * WP;
    if (j >= 34) return;
    int ct = refl(colp - 1, W);        // true column this padded col represents
    int grow = refl(r0 - 1 + j, H);

    float y10 = 0.f, y11 = 0.f;
#pragma unroll
    for (int i = 0; i < 2; ++i) {
        long long xb = (long long)(b * CCH + 2 * g + i) * H * W;
        float m = xm[i], r = xr[i];
#pragma unroll
        for (int kr = 0; kr < 3; ++kr) {
            int rr = refl(grow + kr - 1, H) * W;
#pragma unroll
            for (int kc = 0; kc < 3; ++kc) {
                int cc = refl(ct + kc - 1, W);
                float xv = (ldv(x, xb + rr + cc, isbf) - m) * r;
                y10 += xv * sw[i * 9 + kr * 3 + kc];
                y11 += xv * sw[18 + i * 9 + kr * 3 + kc];
            }
        }
    }
    band[((long long)(b * CCH + 2 * g) * 34 + j) * WS + colp] = pw[0] * y10 + pw[1] * y11 + bs[0];
    band[((long long)(b * CCH + 2 * g + 1) * 34 + j) * WS + colp] = pw[2] * y10 + pw[3] * y11 + bs[1];
}

// ---------------------------------------------------------------------------
// K5: LDS-staged register-tiled shared 3x3 conv 128->128 + bias, v2.
// Band is pre-padded (K4), so stage loads, ds_writes and ds_reads are ALL
// 16B-aligned b128 (uniform 8-way bank spread = bandwidth floor, no conflict).
// Staging is register double-buffered (A/B sets): chunk i+1 global loads issue
// before chunk i compute, hiding L2 latency under FMAs.
// Block: 256 thr = 16x16; thread = 2 rows x 4 cols x 4 ocs. Tile 32x64x4oc.
// LDS: wsh 18432 B + ins [4][34][68] 36992 B = 55424 B -> 2 blocks/CU.
__global__ __launch_bounds__(256, 2) void bigconv_tile_kernel(
    const int* flag, const float* __restrict__ band,
    const void* cw, const void* cb, void* out, long long ooff,
    int H, int W, int WS, int r0, long long bandstride) {
    int isbf = flag[0];
    int ctiles = W >> 6;
    int per_band = BB * 32 * ctiles;
    int t = blockIdx.x;
    int bandidx = t / per_band;
    int rem = t - bandidx * per_band;
    int b = rem / (32 * ctiles);
    int rem2 = rem - b * (32 * ctiles);
    int ocb = rem2 / ctiles;
    int tx0 = (rem2 - ocb * ctiles) << 6;
    int rr0 = r0 + 32 * bandidx;
    const float* bandb = band + bandidx * bandstride + (long long)b * CCH * 34 * WS;

    int tid = threadIdx.x;
    int tr = tid >> 4;   // 0..15
    int tc = tid & 15;   // 0..15

    __shared__ float wsh[4608];   // [ic][ol*9+k]
    __shared__ float ins[9248];   // [4][34][68]; cols 0..63 body, 64..65 halo-R pair

    for (int idx = tid; idx < 4608; idx += 256) {
        int ic = idx / 36;
        int r = idx - ic * 36;
        int ol = r / 9;
        int k = r - ol * 9;
        wsh[idx] = ldv(cw, ((long long)(ocb * 4 + ol) * CCH + ic) * 9 + k, isbf);
    }

    float acc[32];  // [ol][py][px]
#pragma unroll
    for (int ol = 0; ol < 4; ++ol) {
        float bv = ldv(cb, ocb * 4 + ol, isbf);
#pragma unroll
        for (int p = 0; p < 8; ++p) acc[ol * 8 + p] = bv;
    }

    // ---- hoisted per-thread constants (chunk-invariant) ----
    // body: row for slot k is rowid=k*16+tr (k==8 valid only for tr<8)
    int lwoff[9];
#pragma unroll
    for (int k = 0; k < 9; ++k) {
        int rowid = k * 16 + tr;
        int icl = rowid / 34;
        int rr = rowid - icl * 34;
        lwoff[k] = icl * 2312 + rr * 68 + tc * 4;
    }
    const float* gbase = bandb + tx0 + tc * 4;  // body base (16B aligned)
    // halo: h in 0..271 -> (row h>>1, side h&1); thread covers h=tid and (tid<16) h=256+tid
    int rh0 = tid >> 1, sd0 = tid & 1;
    int i0 = rh0 / 34;
    int lh0 = i0 * 2312 + (rh0 - i0 * 34) * 68 + 64 + sd0;
    long long gh0 = (long long)rh0 * WS + tx0 + 64 + sd0;
    int rh1 = 128 + (tid >> 1), sd1 = tid & 1;
    int i1 = rh1 / 34;
    int lh1 = i1 * 2312 + (rh1 - i1 * 34) * 68 + 64 + sd1;
    long long gh1 = (long long)rh1 * WS + tx0 + 64 + sd1;
    long long cstep = 136LL * WS;  // rows per chunk

#define BC_LOADS(BV, HV, ICC)                                                        \
    {                                                                                \
        const float* pc_ = gbase + (long long)(ICC) * cstep;                         \
        _Pragma("unroll") for (int k = 0; k < 9; ++k) {                              \
            if (k < 8 || tr < 8)                                                     \
                BV[k] = *reinterpret_cast<const float4*>(pc_ + (k * 16 + tr) * WS);  \
        }                                                                            \
        HV[0] = bandb[(long long)(ICC) * cstep + gh0];                               \
        if (tid < 16) HV[1] = bandb[(long long)(ICC) * cstep + gh1];                 \
    }

#define BC_WRITES(BV, HV)                                                            \
    {                                                                                \
        _Pragma("unroll") for (int k = 0; k < 9; ++k) {                              \
            if (k < 8 || tr < 8) *reinterpret_cast<float4*>(&ins[lwoff[k]]) = BV[k]; \
        }                                                                            \
        ins[lh0] = HV[0];                                                            \
        if (tid < 16) ins[lh1] = HV[1];                                              \
    }

#define BC_COMPUTE(ICC)                                                              \
    _Pragma("unroll") for (int icl = 0; icl < 4; ++icl) {                            \
        float win[32];                                                               \
        const float* ip_ = &ins[icl * 2312 + (tr * 2) * 68 + tc * 4];                \
        _Pragma("unroll") for (int jj = 0; jj < 4; ++jj) {                           \
            float4 lo = *reinterpret_cast<const float4*>(ip_ + jj * 68);             \
            float4 hi = *reinterpret_cast<const float4*>(ip_ + jj * 68 + 4);         \
            win[jj * 8 + 0] = lo.x; win[jj * 8 + 1] = lo.y;                          \
            win[jj * 8 + 2] = lo.z; win[jj * 8 + 3] = lo.w;                          \
            win[jj * 8 + 4] = hi.x; win[jj * 8 + 5] = hi.y;                          \
            win[jj * 8 + 6] = hi.z; win[jj * 8 + 7] = hi.w;                          \
        }                                                                            \
        const float* wp_ = &wsh[((ICC) * 4 + icl) * 36];                             \
        _Pragma("unroll") for (int ol = 0; ol < 4; ++ol) {                           \
            float wr[9];                                                             \
            _Pragma("unroll") for (int k = 0; k < 9; ++k) wr[k] = wp_[ol * 9 + k];   \
            _Pragma("unroll") for (int py = 0; py < 2; ++py)                         \
                _Pragma("unroll") for (int px = 0; px < 4; ++px) {                   \
                    float a = acc[ol * 8 + py * 4 + px];                             \
                    _Pragma("unroll") for (int kr = 0; kr < 3; ++kr)                 \
                        _Pragma("unroll") for (int kc = 0; kc < 3; ++kc)             \
                            a += win[(py + kr) * 8 + px + kc] * wr[kr * 3 + kc];     \
                    acc[ol * 8 + py * 4 + px] = a;                                   \
                }                                                                    \
        }                                                                            \
    }

    float4 bvA[9], bvB[9];
    float hA[2], hB[2];
    BC_LOADS(bvA, hA, 0);

#pragma unroll 1
    for (int ii = 0; ii < 16; ++ii) {
        int icc0 = ii * 2;
        __syncthreads();            // prev compute done with ins (also covers wsh init)
        BC_WRITES(bvA, hA);
        __syncthreads();            // chunk icc0 ready
        BC_LOADS(bvB, hB, icc0 + 1);   // overlaps compute below
        BC_COMPUTE(icc0);
        __syncthreads();
        BC_WRITES(bvB, hB);
        __syncthreads();
        if (ii < 15) BC_LOADS(bvA, hA, icc0 + 2);
        BC_COMPUTE(icc0 + 1);
    }
#undef BC_LOADS
#undef BC_WRITES
#undef BC_COMPUTE

#pragma unroll
    for (int ol = 0; ol < 4; ++ol) {
        long long oco = ooff + (long long)(b * CCH + ocb * 4 + ol) * H * W;
#pragma unroll
        for (int py = 0; py < 2; ++py) {
            long long rowo = oco + (long long)(rr0 + tr * 2 + py) * W + tx0 + tc * 4;
#pragma unroll
            for (int px = 0; px < 4; ++px)
                stv(out, rowo + px, isbf, acc[ol * 8 + py * 4 + px]);
        }
    }
}

// ---------------------------------------------------------------------------
// K6: final instance-norm + leaky relu, in place on d_out.
__global__ __launch_bounds__(256) void finalize_kernel(const int* flag, void* y, long long off,
                                                       const float* __restrict__ stat,
                                                       int HW, long long total) {
    long long idx = (long long)blockIdx.x * 256 + threadIdx.x;
    if (idx >= total) return;
    int isbf = flag[0];
    int bc = (int)(idx / HW);
    float m = stat[bc * 2];
    float r = stat[bc * 2 + 1];
    float v = (ldv(y, off + idx, isbf) - m) * r;
    stv(y, off + idx, isbf, v >= 0.f ? v : 0.2f * v);
}

// ---------------------------------------------------------------------------
extern "C" void kernel_launch(void* const* d_in, const int* in_sizes, int n_in,
                              void* d_out, int out_size, void* d_ws, size_t ws_size,
                              hipStream_t stream) {
    const void* c_hf = d_in[0];
    const void* c_lf = d_in[1];
    const void* s_hf = d_in[2];
    const void* s_lf = d_in[3];
    const void* kp_h_sp_w = d_in[4];
    const void* kp_h_sp_b = d_in[5];
    const void* kp_h_pw_w = d_in[6];
    const void* kp_h_pw_b = d_in[7];
    const void* kp_h_b_w = d_in[8];
    const void* kp_h_b_b = d_in[9];
    const void* kp_l_sp_w = d_in[10];
    const void* kp_l_sp_b = d_in[11];
    const void* kp_l_pw_w = d_in[12];
    const void* kp_l_pw_b = d_in[13];
    const void* kp_l_b_w = d_in[14];
    const void* kp_l_b_b = d_in[15];
    const void* conv_h_w = d_in[16];
    const void* conv_h_b = d_in[17];
    const void* conv_l_w = d_in[18];
    const void* conv_l_b = d_in[19];

    int* flag = (int*)d_ws;
    float* f = (float*)d_ws;
    float* sm_h = f + 64;
    float* sm_l = f + 2112;
    float* wsp_h = f + 4160;
    float* wsp_l = f + 13376;
    float* wpw_h = f + 22592;
    float* wpw_l = f + 23616;
    float* bias_h = f + 24640;
    float* bias_l = f + 25152;
    float* xstat_h = f + 25664;
    float* xstat_l = f + 26688;
    float* ystat_h = f + 27712;
    float* ystat_l = f + 28736;
    float* band = (float*)((char*)d_ws + 131072);  // hf padded band: 4*128*34*264 f32 = 19.3 MB

    const int HWH = 256 * 256, HWL = 128 * 128;
    const int WSH = 256 + 8, WSL = 128 + 8;         // padded band row strides
    const long long OFF_L = 33554432LL;             // element offset of ol in d_out
    const long long BSTR_L = 4LL * 128 * 34 * WSL;  // lf band region stride (floats)

    detect_kernel<<<1, 256, 0, stream>>>(c_hf, flag);

    // predictors
    sm_kernel<<<8, 256, 0, stream>>>(flag, s_hf, sm_h);
    sm_kernel<<<8, 256, 0, stream>>>(flag, s_lf, sm_l);
    spconv_kernel<<<1024, 256, 0, stream>>>(flag, s_hf, kp_h_sp_w, kp_h_sp_b, wsp_h);
    spconv_kernel<<<1024, 256, 0, stream>>>(flag, s_lf, kp_l_sp_w, kp_l_sp_b, wsp_l);
    pwbias_kernel<<<6, 256, 0, stream>>>(flag, sm_h, kp_h_pw_w, kp_h_pw_b, kp_h_b_w, kp_h_b_b, wpw_h, bias_h);
    pwbias_kernel<<<6, 256, 0, stream>>>(flag, sm_l, kp_l_pw_w, kp_l_pw_b, kp_l_b_w, kp_l_b_b, wpw_l, bias_l);

    // input instance-norm stats
    stats_kernel<<<512, 256, 0, stream>>>(flag, c_hf, 0, xstat_h, HWH);
    stats_kernel<<<512, 256, 0, stream>>>(flag, c_lf, 0, xstat_l, HWL);

    // grouped_band grids: bg(256) x ceil(34*(W+2)/256)
    const int GB_H = 256 * ((34 * (256 + 2) + 255) >> 8);  // 256*35
    const int GB_L = 256 * ((34 * (128 + 2) + 255) >> 8);  // 256*18

    // hf: 8 bands of 32 rows; bigconv tile kernel 512 blocks = 2/CU
    for (int r0 = 0; r0 < 256; r0 += 32) {
        grouped_band_kernel<<<GB_H, 256, 0, stream>>>(flag, c_hf, xstat_h, wsp_h, wpw_h,
                                                      bias_h, band, 256, 256, WSH, r0);
        bigconv_tile_kernel<<<512, 256, 0, stream>>>(flag, band, conv_h_w, conv_h_b,
                                                     d_out, 0, 256, 256, WSH, r0, 0);
    }
    // lf: 2 iterations, each with two 32-row bands resident -> 512-block bigconv
    for (int r0 = 0; r0 < 128; r0 += 64) {
        grouped_band_kernel<<<GB_L, 256, 0, stream>>>(flag, c_lf, xstat_l, wsp_l, wpw_l,
                                                      bias_l, band, 128, 128, WSL, r0);
        grouped_band_kernel<<<GB_L, 256, 0, stream>>>(flag, c_lf, xstat_l, wsp_l, wpw_l,
                                                      bias_l, band + BSTR_L, 128, 128, WSL, r0 + 32);
        bigconv_tile_kernel<<<512, 256, 0, stream>>>(flag, band, conv_l_w, conv_l_b,
                                                     d_out, OFF_L, 128, 128, WSL, r0, BSTR_L);
    }

    // output instance-norm stats + finalize in place
    stats_kernel<<<512, 256, 0, stream>>>(flag, d_out, 0, ystat_h, HWH);
    stats_kernel<<<512, 256, 0, stream>>>(flag, d_out, OFF_L, ystat_l, HWL);
    finalize_kernel<<<131072, 256, 0, stream>>>(flag, d_out, 0, ystat_h, HWH, (long long)BB * CCH * HWH);
    finalize_kernel<<<32768, 256, 0, stream>>>(flag, d_out, OFF_L, ystat_l, HWL, (long long)BB * CCH * HWL);
}